// Round 1
// baseline (166.324 us; speedup 1.0000x reference)
//
#include <hip/hip_runtime.h>
#include <hip/hip_bf16.h>
#include <math.h>

#define M_   8
#define A_   48
#define NS   4
#define NR   16   // ShfR count
#define NA   4    // ShfA count
#define NZ   8    // ShfZ count
#define NP   10   // species pair channels
#define RAD  (NS*NR)          // 64
#define ANG  (NP*NA*NZ)       // 320
#define OUTL (RAD+ANG)        // 384
#define RCRf 5.2f
#define RCAf 3.5f
#define PI_F 3.14159265358979323846f

// dtype-agnostic scalar load: bf16 (ushort<<16) or fp32
__device__ __forceinline__ float ldf(const void* p, int i, int bf) {
    if (bf) {
        unsigned int w = ((unsigned int)((const unsigned short*)p)[i]) << 16;
        return __uint_as_float(w);
    }
    return ((const float*)p)[i];
}

__global__ __launch_bounds__(64) void aev_kernel(
    const void* coords, const void* etaR_p, const void* shfR_p,
    const void* etaA_p, const void* zeta_p, const void* shfA_p,
    const void* shfZ_p, const int* species, const int* triu,
    void* out)
{
    const int bid = blockIdx.x;          // m*A_ + center index
    const int m   = bid / A_;
    const int ci  = bid % A_;
    const int tid = threadIdx.x;

    // runtime dtype probe: EtaR==16.0 ; fp32 LE first ushort==0x0000, bf16==0x4180
    const int bf = (((const unsigned short*)etaR_p)[0] != 0);

    __shared__ float sx[A_], sy[A_], sz[A_];
    __shared__ int   ssp[A_];
    __shared__ float vx[A_], vy[A_], vz[A_], dd[A_], fca[A_];
    __shared__ int   mR[A_], mA[A_];
    __shared__ float acc[OUTL];
    __shared__ float shfR_s[NR], shfA_s[NA], czs[NZ], szs[NZ];
    __shared__ int   triu_s[NS*NS];

    if (tid < A_) {
        int base = (m*A_ + tid)*3;
        sx[tid]  = ldf(coords, base+0, bf);
        sy[tid]  = ldf(coords, base+1, bf);
        sz[tid]  = ldf(coords, base+2, bf);
        ssp[tid] = species[m*A_ + tid];
    }
    if (tid < NR) shfR_s[tid] = ldf(shfR_p, tid, bf);
    if (tid < NA) shfA_s[tid] = ldf(shfA_p, tid, bf);
    if (tid < NZ) {
        float z = ldf(shfZ_p, tid, bf);
        czs[tid] = cosf(z);
        szs[tid] = sinf(z);
    }
    if (tid < NS*NS) triu_s[tid] = triu[tid];
    for (int c = tid; c < OUTL; c += 64) acc[c] = 0.0f;
    __syncthreads();

    const float etaR = ldf(etaR_p, 0, bf);
    const float etaA = ldf(etaA_p, 0, bf);
    const float zeta = ldf(zeta_p, 0, bf);

    const float cx = sx[ci], cy = sy[ci], cz0 = sz[ci];
    const int valid_i = (ssp[ci] >= 0);

    if (tid < A_) {
        int j = tid;
        float ax = sx[j]-cx, ay = sy[j]-cy, az = sz[j]-cz0;
        float d2 = ax*ax + ay*ay + az*az;
        float d  = sqrtf(d2 > 0.0f ? d2 : 1.0f);   // matches jnp.where(d2>0,d2,1)
        vx[j]=ax; vy[j]=ay; vz[j]=az; dd[j]=d;
        int pv = valid_i && (ssp[j] >= 0) && (j != ci);
        mR[j] = pv && (d <= RCRf);
        mA[j] = pv && (d <= RCAf);
        fca[j] = 0.5f*__cosf(d*(PI_F/RCAf)) + 0.5f;
    }
    __syncthreads();

    // ---- radial: 48 neighbors x 16 shells ----
    for (int idx = tid; idx < A_*NR; idx += 64) {
        int j = idx >> 4;
        int r = idx & 15;
        if (!mR[j]) continue;
        float d  = dd[j];
        float fc = 0.5f*__cosf(d*(PI_F/RCRf)) + 0.5f;
        float t  = d - shfR_s[r];
        float rt = 0.25f*__expf(-etaR*t*t)*fc;
        atomicAdd(&acc[ssp[j]*NR + r], rt);
    }

    // ---- angular: pairs (j<k) x 4 ShfA x 8 ShfZ ----
    for (int jk = tid; jk < A_*A_; jk += 64) {
        int j = jk / A_;
        int k = jk - j*A_;
        if (k <= j) continue;
        if (!(mA[j] && mA[k])) continue;
        float dj = dd[j], dk = dd[k];
        float dot = vx[j]*vx[k] + vy[j]*vy[k] + vz[j]*vz[k];
        float c = 0.95f * dot / (dj*dk);
        c = fminf(0.99f, fmaxf(-0.99f, c));
        // cos(arccos(c) - z) = c*cos z + sqrt(1-c^2)*sin z  (arccos in [0,pi])
        float s = sqrtf(1.0f - c*c);
        float davg = 0.5f*(dj + dk);
        float base = 2.0f * fca[j]*fca[k];
        int p = triu_s[ssp[j]*NS + ssp[k]];
        float* accp = &acc[RAD + p*(NA*NZ)];
        #pragma unroll
        for (int za = 0; za < NA; ++za) {
            float t  = davg - shfA_s[za];
            float f2 = __expf(-etaA*t*t) * base;
            #pragma unroll
            for (int zz = 0; zz < NZ; ++zz) {
                float cd = c*czs[zz] + s*szs[zz];
                float x  = 0.5f*(1.0f + cd);
                float f1 = __powf(x, zeta);
                atomicAdd(&accp[za*NZ + zz], f1*f2);
            }
        }
    }
    __syncthreads();

    // ---- write out: 384 contiguous per center ----
    long obase = (long)bid * OUTL;
    if (bf) {
        __hip_bfloat16* o = (__hip_bfloat16*)out;
        for (int c = tid; c < OUTL; c += 64)
            o[obase + c] = __float2bfloat16(acc[c]);
    } else {
        float* o = (float*)out;
        for (int c = tid; c < OUTL; c += 64)
            o[obase + c] = acc[c];
    }
}

extern "C" void kernel_launch(void* const* d_in, const int* in_sizes, int n_in,
                              void* d_out, int out_size, void* d_ws, size_t ws_size,
                              hipStream_t stream) {
    (void)in_sizes; (void)n_in; (void)d_ws; (void)ws_size; (void)out_size;
    aev_kernel<<<M_*A_, 64, 0, stream>>>(
        d_in[0], d_in[1], d_in[2], d_in[3], d_in[4], d_in[5], d_in[6],
        (const int*)d_in[7], (const int*)d_in[8], d_out);
}

// Round 2
// 79.041 us; speedup vs baseline: 2.1043x; 2.1043x over previous
//
#include <hip/hip_runtime.h>
#include <hip/hip_bf16.h>
#include <math.h>

#define M_   8
#define A_   48
#define NS   4
#define NR   16   // ShfR count
#define NA   4    // ShfA count
#define NZ   8    // ShfZ count
#define NP   10   // species pair channels
#define RAD  (NS*NR)          // 64
#define ANG  (NP*NA*NZ)       // 320
#define OUTL (RAD+ANG)        // 384
#define NPMAX 1128            // C(48,2)
#define RCRf 5.2f
#define RCAf 3.5f
#define PI_F 3.14159265358979323846f

// dtype-agnostic scalar load: bf16 (ushort<<16) or fp32
__device__ __forceinline__ float ldf(const void* p, int i, int bf) {
    if (bf) {
        unsigned int w = ((unsigned int)((const unsigned short*)p)[i]) << 16;
        return __uint_as_float(w);
    }
    return ((const float*)p)[i];
}

__global__ __launch_bounds__(256) void aev_kernel(
    const void* coords, const void* etaR_p, const void* shfR_p,
    const void* etaA_p, const void* zeta_p, const void* shfA_p,
    const void* shfZ_p, const int* species, const int* triu,
    void* out)
{
    const int bid = blockIdx.x;          // m*A_ + center index
    const int m   = bid / A_;
    const int ci  = bid % A_;
    const int tid = threadIdx.x;

    // runtime dtype probe: EtaR==16.0 ; fp32 LE first ushort==0x0000, bf16==0x4180
    const int bf = (((const unsigned short*)etaR_p)[0] != 0);

    __shared__ float sx[A_], sy[A_], sz[A_];
    __shared__ int   ssp[A_];
    __shared__ float vx[A_], vy[A_], vz[A_], dd[A_], fca[A_], fcr[A_];
    __shared__ int   mR[A_], mA[A_];
    __shared__ float acc[OUTL];
    __shared__ float shfR_s[NR], shfA_s[NA], czs[NZ], szs[NZ];
    __shared__ int   triu_s[NS*NS];
    // compacted valid angular pairs
    __shared__ int   cnt;
    __shared__ float pc[NPMAX], ps[NPMAX], pdavg[NPMAX], pbase[NPMAX];
    __shared__ int   pp[NPMAX];
    // per-thread-exclusive angular accumulators: priv[p][tid]
    __shared__ float priv[NP*256];

    if (tid < A_) {
        int base = (m*A_ + tid)*3;
        sx[tid]  = ldf(coords, base+0, bf);
        sy[tid]  = ldf(coords, base+1, bf);
        sz[tid]  = ldf(coords, base+2, bf);
        ssp[tid] = species[m*A_ + tid];
    }
    if (tid < NR) shfR_s[tid] = ldf(shfR_p, tid, bf);
    if (tid < NA) shfA_s[tid] = ldf(shfA_p, tid, bf);
    if (tid < NZ) {
        float z = ldf(shfZ_p, tid, bf);
        czs[tid] = cosf(z);
        szs[tid] = sinf(z);
    }
    if (tid < NS*NS) triu_s[tid] = triu[tid];
    if (tid == 0) cnt = 0;
    for (int c = tid; c < OUTL; c += 256) acc[c] = 0.0f;
    #pragma unroll
    for (int p = 0; p < NP; ++p) priv[p*256 + tid] = 0.0f;
    __syncthreads();

    const float etaR = ldf(etaR_p, 0, bf);
    const float etaA = ldf(etaA_p, 0, bf);
    const float zeta = ldf(zeta_p, 0, bf);
    const int   z32  = (zeta == 32.0f);

    const float cx = sx[ci], cy = sy[ci], cz0 = sz[ci];
    const int valid_i = (ssp[ci] >= 0);

    if (tid < A_) {
        int j = tid;
        float ax = sx[j]-cx, ay = sy[j]-cy, az = sz[j]-cz0;
        float d2 = ax*ax + ay*ay + az*az;
        float d  = sqrtf(d2 > 0.0f ? d2 : 1.0f);   // matches jnp.where(d2>0,d2,1)
        vx[j]=ax; vy[j]=ay; vz[j]=az; dd[j]=d;
        int pv = valid_i && (ssp[j] >= 0) && (j != ci);
        mR[j] = pv && (d <= RCRf);
        mA[j] = pv && (d <= RCAf);
        fca[j] = 0.5f*__cosf(d*(PI_F/RCAf)) + 0.5f;
        fcr[j] = 0.5f*__cosf(d*(PI_F/RCRf)) + 0.5f;
    }
    __syncthreads();

    // ---- radial: 48 neighbors x 16 shells (768 terms) ----
    for (int idx = tid; idx < A_*NR; idx += 256) {
        int j = idx >> 4;
        int r = idx & 15;
        if (!mR[j]) continue;
        float t  = dd[j] - shfR_s[r];
        float rt = 0.25f*__expf(-etaR*t*t)*fcr[j];
        atomicAdd(&acc[ssp[j]*NR + r], rt);
    }

    // ---- compact valid angular pairs, precompute per-pair data ----
    for (int idx = tid; idx < A_*A_; idx += 256) {
        int j = idx / A_;
        int k = idx - j*A_;
        if (k <= j) continue;
        if (!(mA[j] && mA[k])) continue;
        int slot = atomicAdd(&cnt, 1);
        float dj = dd[j], dk = dd[k];
        float dot = vx[j]*vx[k] + vy[j]*vy[k] + vz[j]*vz[k];
        float c = 0.95f * dot / (dj*dk);
        c = fminf(0.99f, fmaxf(-0.99f, c));
        pc[slot]    = c;
        ps[slot]    = sqrtf(1.0f - c*c);  // sin(arccos(c)), arccos in [0,pi]
        pdavg[slot] = 0.5f*(dj + dk);
        pbase[slot] = 2.0f * fca[j]*fca[k];
        pp[slot]    = triu_s[ssp[j]*NS + ssp[k]];
    }
    __syncthreads();

    // ---- angular: thread owns term (tid&31) for pair-lane (tid>>5) ----
    {
        const int term = tid & 31;          // za*8+zz
        const int za   = term >> 3;
        const int zz   = term & 7;
        const int lane = tid >> 5;          // 0..7
        const float czt = czs[zz], szt = szs[zz];
        const float shfAt = shfA_s[za];
        const float negEtaA = -etaA;
        const int n = cnt;
        float* mypriv = &priv[tid];
        for (int pi = lane; pi < n; pi += 8) {
            float c    = pc[pi];            // broadcast reads (same addr per group)
            float s    = ps[pi];
            float t    = pdavg[pi] - shfAt;
            float f2   = __expf(negEtaA*t*t) * pbase[pi];
            float cd   = c*czt + s*szt;     // cos(ang - ShfZ)
            float x    = 0.5f + 0.5f*cd;
            float f1;
            if (z32) {                      // x^32 = 5 squarings (zeta==32 fast path)
                float x2 = x*x, x4 = x2*x2, x8 = x4*x4, x16 = x8*x8;
                f1 = x16*x16;
            } else {
                f1 = __powf(x, zeta);
            }
            mypriv[pp[pi]*256] += f1*f2;    // exclusive slot, no atomic
        }
    }
    __syncthreads();

    // ---- reduce priv over the 8 pair-lanes into acc[RAD + p*32 + term] ----
    for (int c = tid; c < ANG; c += 256) {
        int p    = c >> 5;
        int term = c & 31;
        const float* pr = &priv[p*256 + term];
        float v = 0.0f;
        #pragma unroll
        for (int g = 0; g < 8; ++g) v += pr[g*32];
        acc[RAD + c] = v;
    }
    __syncthreads();

    // ---- write out: 384 contiguous per center ----
    long obase = (long)bid * OUTL;
    if (bf) {
        __hip_bfloat16* o = (__hip_bfloat16*)out;
        for (int c = tid; c < OUTL; c += 256)
            o[obase + c] = __float2bfloat16(acc[c]);
    } else {
        float* o = (float*)out;
        for (int c = tid; c < OUTL; c += 256)
            o[obase + c] = acc[c];
    }
}

extern "C" void kernel_launch(void* const* d_in, const int* in_sizes, int n_in,
                              void* d_out, int out_size, void* d_ws, size_t ws_size,
                              hipStream_t stream) {
    (void)in_sizes; (void)n_in; (void)d_ws; (void)ws_size; (void)out_size;
    aev_kernel<<<M_*A_, 256, 0, stream>>>(
        d_in[0], d_in[1], d_in[2], d_in[3], d_in[4], d_in[5], d_in[6],
        (const int*)d_in[7], (const int*)d_in[8], d_out);
}